// Round 6
// baseline (137.099 us; speedup 1.0000x reference)
//
#include <hip/hip_runtime.h>
#include <math.h>

#define TEMP_INV 0.2f
#define BIAS 0.0001f
#define MAGIC 0x5EEDBEA7u
#define MAX_BLOCKS 2048
#define GO_SLOTS 64           // replicated release word, one per 128B line
#define GO_STRIDE 32          // 32 u32 = 128 B
#define SPIN_CAP (1L << 22)   // anti-hang escape: fail visibly, don't hang harness

__device__ __forceinline__ unsigned ld_agent(const unsigned* p) {
    return __hip_atomic_load(p, __ATOMIC_RELAXED, __HIP_MEMORY_SCOPE_AGENT);
}
__device__ __forceinline__ void st_agent(unsigned* p, unsigned v) {
    __hip_atomic_store(p, v, __ATOMIC_RELAXED, __HIP_MEMORY_SCOPE_AGENT);
}

// Single normal-launch kernel, low-congestion device barrier:
//   Phase 1: s1[n]=ne[n].W[0:128], s2[n]=ne[n].W[128:256] (+ srel, shq tables)
//   barrier (spread flags, replicated go-lines, slow polls)
//   Phase 2: per-edge Gumbel-sigmoid gate
__global__ __launch_bounds__(256, 8) void fused_all_kernel(
        const float* __restrict__ ne,
        const float* __restrict__ R,
        const float* __restrict__ W,
        const float* __restrict__ bias_ptr,
        const int* __restrict__ h_index,
        const int* __restrict__ r_index,
        const int* __restrict__ rows,
        const int* __restrict__ cols,
        const int* __restrict__ etype,
        const int* __restrict__ bid,
        const float* __restrict__ eps_u,
        float* __restrict__ s1,
        float* __restrict__ s2,
        float* __restrict__ srel,
        float* __restrict__ shq,
        unsigned* __restrict__ flags_in,
        unsigned* __restrict__ flags_done,
        unsigned* __restrict__ go_slots,
        float* __restrict__ out,
        int n_nodes, int num_rel, int B, int E) {
    const int lane   = threadIdx.x & 63;
    const int l32    = lane & 31;
    const int half   = lane >> 5;
    const int wid    = (blockIdx.x * blockDim.x + threadIdx.x) >> 6;
    const int nwaves = (gridDim.x * blockDim.x) >> 6;

    // ---------------- Phase 1: dots (R3 body) ----------------
    {
        const int npairs = (n_nodes + 1) >> 1;
        const int supers = (npairs + 3) >> 2;
        const int total  = supers + num_rel + B;

        const float4* W4 = (const float4*)W;
        const float4 w1 = W4[l32];        // W[0:128]
        const float4 w2 = W4[32 + l32];   // W[128:256]

        for (int t = wid; t < total; t += nwaves) {
            if (t < supers) {
                const int pair0 = t * 4;
                float4 e[4];
                int node[4];
                #pragma unroll
                for (int j = 0; j < 4; ++j) {
                    node[j] = (pair0 + j) * 2 + half;
                    e[j] = make_float4(0.f, 0.f, 0.f, 0.f);
                    if (node[j] < n_nodes)
                        e[j] = ((const float4*)(ne + (size_t)node[j] * 128))[l32];
                }
                #pragma unroll
                for (int j = 0; j < 4; ++j) {
                    const float p1 = e[j].x * w1.x + e[j].y * w1.y + e[j].z * w1.z + e[j].w * w1.w;
                    const float p2 = e[j].x * w2.x + e[j].y * w2.y + e[j].z * w2.z + e[j].w * w2.w;
                    const float q1 = __shfl_xor(p1, 16);
                    const float q2 = __shfl_xor(p2, 16);
                    float a = (l32 < 16) ? (p1 + q1) : (p2 + q2);
                    a += __shfl_xor(a, 8);
                    a += __shfl_xor(a, 4);
                    a += __shfl_xor(a, 2);
                    a += __shfl_xor(a, 1);
                    if (node[j] < n_nodes) {
                        if (l32 == 0)       s1[node[j]] = a;
                        else if (l32 == 16) s2[node[j]] = a;
                    }
                }
            } else if (t < supers + num_rel) {
                const int r = t - supers;
                const float2* W2 = (const float2*)W;
                const float2 w3 = W2[128 + lane];  // W[256:384]
                const float2 e  = ((const float2*)(R + (size_t)r * 128))[lane];
                float p = e.x * w3.x + e.y * w3.y;
                #pragma unroll
                for (int off = 32; off; off >>= 1) p += __shfl_xor(p, off);
                if (lane == 0) srel[r] = p;
            } else {
                const int bb = t - supers - num_rel;
                const float2* W2 = (const float2*)W;
                const float2 w4 = W2[192 + lane];  // W[384:512]
                const float2 w5 = W2[256 + lane];  // W[512:640]
                const float2 h  = ((const float2*)(ne + (size_t)h_index[bb] * 128))[lane];
                const float2 q  = ((const float2*)(R  + (size_t)r_index[bb] * 128))[lane];
                float p = h.x * w4.x + h.y * w4.y + q.x * w5.x + q.y * w5.y;
                #pragma unroll
                for (int off = 32; off; off >>= 1) p += __shfl_xor(p, off);
                if (lane == 0) shq[bb] = p + bias_ptr[0];
            }
        }
    }

    // ---------------- Device barrier (low-congestion) ----------------
    __syncthreads();
    if (threadIdx.x == 0) {
        __threadfence();                          // release s1/s2/srel/shq
        st_agent(&flags_in[blockIdx.x], MAGIC);
    }
    if (blockIdx.x == 0) {
        // 256 threads scan the arrival flags (spread over 16+ cache lines)
        for (int s = threadIdx.x; s < gridDim.x; s += blockDim.x) {
            long guard = 0;
            while (ld_agent(&flags_in[s]) != MAGIC) {
                __builtin_amdgcn_s_sleep(8);
                if (++guard > SPIN_CAP) break;
            }
        }
        __syncthreads();
        // replicate release word across 64 distinct lines
        if (threadIdx.x < GO_SLOTS) {
            __threadfence();
            st_agent(&go_slots[threadIdx.x * GO_STRIDE], MAGIC);
        }
    } else if (threadIdx.x == 0) {
        const unsigned* myGo = &go_slots[(blockIdx.x & (GO_SLOTS - 1)) * GO_STRIDE];
        long guard = 0;
        do {
            __builtin_amdgcn_s_sleep(64);         // sleep FIRST, poll slow (~4k cy)
            if (++guard > SPIN_CAP) break;
        } while (ld_agent(myGo) != MAGIC);
    }
    __syncthreads();
    __threadfence();                              // acquire for all threads

    // ---------------- Phase 2: edge gate, 2 edges/thread (R3 body) ----------------
    {
        const int tid      = blockIdx.x * blockDim.x + threadIdx.x;
        const int nthreads = gridDim.x * blockDim.x;
        const int npair_e  = E >> 1;          // E even (500000)
        for (int p = tid; p < npair_e; p += nthreads) {
            const int2   r2 = ((const int2*)rows)[p];
            const int2   c2 = ((const int2*)cols)[p];
            const int2   t2 = ((const int2*)etype)[p];
            const int2   b2 = ((const int2*)bid)[p];
            const float2 u2 = ((const float2*)eps_u)[p];
            const float a0 = s1[r2.x],   a1 = s1[r2.y];
            const float c0 = s2[c2.x],   c1 = s2[c2.y];
            const float e0 = srel[t2.x], e1 = srel[t2.y];
            const float q0 = shq[b2.x],  q1 = shq[b2.y];

            const float eps0   = fmaf(u2.x, (2.0f * BIAS - 1.0f), (1.0f - BIAS));
            const float eps1   = fmaf(u2.y, (2.0f * BIAS - 1.0f), (1.0f - BIAS));
            const float logit0 = __logf(eps0) - __logf(1.0f - eps0);
            const float logit1 = __logf(eps1) - __logf(1.0f - eps1);
            const float g0 = (logit0 + a0 + c0 + e0 + q0) * TEMP_INV;
            const float g1 = (logit1 + a1 + c1 + e1 + q1) * TEMP_INV;
            float2 o;
            o.x = __builtin_amdgcn_rcpf(1.0f + __expf(-g0));
            o.y = __builtin_amdgcn_rcpf(1.0f + __expf(-g1));
            ((float2*)out)[p] = o;
        }
        if ((E & 1) && tid == 0) {
            const int i = E - 1;
            const float sw  = s1[rows[i]] + s2[cols[i]] + srel[etype[i]] + shq[bid[i]];
            const float eps = fmaf(eps_u[i], (2.0f * BIAS - 1.0f), (1.0f - BIAS));
            const float lg  = __logf(eps) - __logf(1.0f - eps);
            const float g   = (lg + sw) * TEMP_INV;
            out[i] = __builtin_amdgcn_rcpf(1.0f + __expf(-g));
        }
    }

    // ---------------- Cleanup: self-reset barrier state (block 0 lingers) ----------------
    __syncthreads();
    if (threadIdx.x == 0) st_agent(&flags_done[blockIdx.x], MAGIC);
    if (blockIdx.x == 0) {
        for (int s = threadIdx.x; s < gridDim.x; s += blockDim.x) {
            long guard = 0;
            while (ld_agent(&flags_done[s]) != MAGIC) {
                __builtin_amdgcn_s_sleep(8);
                if (++guard > SPIN_CAP) break;
            }
        }
        __syncthreads();
        for (int s = threadIdx.x; s < gridDim.x; s += blockDim.x) {
            st_agent(&flags_in[s], 0u);
            st_agent(&flags_done[s], 0u);
        }
        if (threadIdx.x < GO_SLOTS) st_agent(&go_slots[threadIdx.x * GO_STRIDE], 0u);
    }
}

extern "C" void kernel_launch(void* const* d_in, const int* in_sizes, int n_in,
                              void* d_out, int out_size, void* d_ws, size_t ws_size,
                              hipStream_t stream) {
    const float* node_embeds = (const float*)d_in[0];
    const float* R           = (const float*)d_in[1];
    const float* W           = (const float*)d_in[2];
    const float* b           = (const float*)d_in[3];
    const float* eps_u       = (const float*)d_in[4];
    const int*   edge_index  = (const int*)d_in[5];
    const int*   edge_type   = (const int*)d_in[6];
    const int*   batch_id    = (const int*)d_in[7];
    const int*   h_index     = (const int*)d_in[8];
    const int*   r_index     = (const int*)d_in[9];

    const int D       = 128;
    const int n_nodes = in_sizes[0] / D;      // 200000
    const int num_rel = in_sizes[1] / D;      // 200
    const int E       = in_sizes[4];          // 500000
    const int B       = in_sizes[8];          // 256

    const int* rows = edge_index;
    const int* cols = edge_index + E;

    // Grid: target 8 blocks/CU (2048 blocks), verified against occupancy query.
    int blocks_per_cu = 0;
    if (hipOccupancyMaxActiveBlocksPerMultiprocessor(&blocks_per_cu,
            (const void*)fused_all_kernel, 256, 0) != hipSuccess || blocks_per_cu <= 0)
        blocks_per_cu = 2;                    // conservative fallback
    if (blocks_per_cu > 8) blocks_per_cu = 8;
    int grid = 256 * blocks_per_cu;           // MI355X: 256 CUs
    if (grid > MAX_BLOCKS) grid = MAX_BLOCKS;

    // workspace: s1[N]|s2[N]|srel|shq | align 256B | flags_in[MAX] | flags_done[MAX] | go_slots
    float* s1   = (float*)d_ws;
    float* s2   = s1 + n_nodes;
    float* srel = s2 + n_nodes;
    float* shq  = srel + num_rel;
    size_t tbl_bytes = (size_t)(2 * n_nodes + num_rel + B) * sizeof(float);
    tbl_bytes = (tbl_bytes + 255) & ~(size_t)255;
    unsigned* flags_in   = (unsigned*)((char*)d_ws + tbl_bytes);
    unsigned* flags_done = flags_in + MAX_BLOCKS;
    unsigned* go_slots   = flags_done + MAX_BLOCKS;

    hipLaunchKernelGGL(fused_all_kernel, dim3(grid), dim3(256), 0, stream,
                       node_embeds, R, W, b, h_index, r_index,
                       rows, cols, edge_type, batch_id, eps_u,
                       s1, s2, srel, shq,
                       flags_in, flags_done, go_slots,
                       (float*)d_out, n_nodes, num_rel, B, E);
}

// Round 7
// 52.667 us; speedup vs baseline: 2.6031x; 2.6031x over previous
//
#include <hip/hip_runtime.h>
#include <math.h>

#define TEMP_INV 0.2f
#define BIAS 0.0001f
#define MAGIC_A 0x5EEDBEA7u   // arrival
#define MAGIC_D 0xD09EBEEFu   // done
#define GRID_BLOCKS 1024      // 4 blocks/CU on 256 CUs — co-residency guaranteed by launch_bounds
#define GO_SLOTS 64
#define GO_STRIDE 32          // 32 u32 = 128 B per slot line
#define SPIN_CAP (1L << 20)   // fail visibly, never hang

__device__ __forceinline__ unsigned ld_bp(const unsigned* p) {          // bypass L1/L2 (IC)
    return __hip_atomic_load(p, __ATOMIC_RELAXED, __HIP_MEMORY_SCOPE_AGENT);
}
__device__ __forceinline__ void st_bp(unsigned* p, unsigned v) {
    __hip_atomic_store(p, v, __ATOMIC_RELAXED, __HIP_MEMORY_SCOPE_AGENT);
}
__device__ __forceinline__ void st_rel(unsigned* p, unsigned v) {       // release: prior stores reach IC first
    __hip_atomic_store(p, v, __ATOMIC_RELEASE, __HIP_MEMORY_SCOPE_AGENT);
}
__device__ __forceinline__ float ldf_bp(const float* p) {
    return __hip_atomic_load(p, __ATOMIC_RELAXED, __HIP_MEMORY_SCOPE_AGENT);
}
__device__ __forceinline__ void stf_bp(float* p, float v) {
    __hip_atomic_store(p, v, __ATOMIC_RELAXED, __HIP_MEMORY_SCOPE_AGENT);
}

// Single kernel, fence-free grid barrier:
//   Phase 1: s1/s2/srel/shq via IC write-through stores
//   barrier: release-flag per block -> block0 scan -> replicated go lines (all relaxed polls)
//   Phase 2: gathers via IC bypass loads (stale L1/L2 never consulted -> no invalidate needed)
__global__ __launch_bounds__(256, 4) void fused_all_kernel(
        const float* __restrict__ ne,
        const float* __restrict__ R,
        const float* __restrict__ W,
        const float* __restrict__ bias_ptr,
        const int* __restrict__ h_index,
        const int* __restrict__ r_index,
        const int* __restrict__ rows,
        const int* __restrict__ cols,
        const int* __restrict__ etype,
        const int* __restrict__ bid,
        const float* __restrict__ eps_u,
        float* __restrict__ s1,
        float* __restrict__ s2,
        float* __restrict__ srel,
        float* __restrict__ shq,
        unsigned* __restrict__ flags_in,
        unsigned* __restrict__ flags_done,
        unsigned* __restrict__ go_slots,
        float* __restrict__ out,
        int n_nodes, int num_rel, int B, int E) {
    const int lane   = threadIdx.x & 63;
    const int l32    = lane & 31;
    const int half   = lane >> 5;
    const int wid    = (blockIdx.x * blockDim.x + threadIdx.x) >> 6;
    const int nwaves = (gridDim.x * blockDim.x) >> 6;

    // ---------------- Phase 1: dots (R3 body; table writes bypass to IC) ----------------
    {
        const int npairs = (n_nodes + 1) >> 1;
        const int supers = (npairs + 3) >> 2;
        const int total  = supers + num_rel + B;

        const float4* W4 = (const float4*)W;
        const float4 w1 = W4[l32];        // W[0:128]
        const float4 w2 = W4[32 + l32];   // W[128:256]

        for (int t = wid; t < total; t += nwaves) {
            if (t < supers) {
                const int pair0 = t * 4;
                float4 e[4];
                int node[4];
                #pragma unroll
                for (int j = 0; j < 4; ++j) {
                    node[j] = (pair0 + j) * 2 + half;
                    e[j] = make_float4(0.f, 0.f, 0.f, 0.f);
                    if (node[j] < n_nodes)
                        e[j] = ((const float4*)(ne + (size_t)node[j] * 128))[l32];
                }
                #pragma unroll
                for (int j = 0; j < 4; ++j) {
                    const float p1 = e[j].x * w1.x + e[j].y * w1.y + e[j].z * w1.z + e[j].w * w1.w;
                    const float p2 = e[j].x * w2.x + e[j].y * w2.y + e[j].z * w2.z + e[j].w * w2.w;
                    const float q1 = __shfl_xor(p1, 16);
                    const float q2 = __shfl_xor(p2, 16);
                    float a = (l32 < 16) ? (p1 + q1) : (p2 + q2);
                    a += __shfl_xor(a, 8);
                    a += __shfl_xor(a, 4);
                    a += __shfl_xor(a, 2);
                    a += __shfl_xor(a, 1);
                    if (node[j] < n_nodes) {
                        if (l32 == 0)       stf_bp(&s1[node[j]], a);
                        else if (l32 == 16) stf_bp(&s2[node[j]], a);
                    }
                }
            } else if (t < supers + num_rel) {
                const int r = t - supers;
                const float2* W2 = (const float2*)W;
                const float2 w3 = W2[128 + lane];  // W[256:384]
                const float2 e  = ((const float2*)(R + (size_t)r * 128))[lane];
                float p = e.x * w3.x + e.y * w3.y;
                #pragma unroll
                for (int off = 32; off; off >>= 1) p += __shfl_xor(p, off);
                if (lane == 0) stf_bp(&srel[r], p);
            } else {
                const int bb = t - supers - num_rel;
                const float2* W2 = (const float2*)W;
                const float2 w4 = W2[192 + lane];  // W[384:512]
                const float2 w5 = W2[256 + lane];  // W[512:640]
                const float2 h  = ((const float2*)(ne + (size_t)h_index[bb] * 128))[lane];
                const float2 q  = ((const float2*)(R  + (size_t)r_index[bb] * 128))[lane];
                float p = h.x * w4.x + h.y * w4.y + q.x * w5.x + q.y * w5.y;
                #pragma unroll
                for (int off = 32; off; off >>= 1) p += __shfl_xor(p, off);
                if (lane == 0) stf_bp(&shq[bb], p + bias_ptr[0]);
            }
        }
    }

    // ---------------- Fence-free barrier ----------------
    __syncthreads();
    if (threadIdx.x == 0) {
        // RELEASE: all bypass table stores reach IC before this flag does.
        st_rel(&flags_in[blockIdx.x], MAGIC_A);
    }
    if (blockIdx.x == 0) {
        for (int s = threadIdx.x; s < GRID_BLOCKS; s += blockDim.x) {
            long guard = 0;
            while (ld_bp(&flags_in[s]) != MAGIC_A) {
                __builtin_amdgcn_s_sleep(4);
                if (++guard > SPIN_CAP) break;
            }
        }
        __syncthreads();   // all flags observed (loads resolved) before go stores issue
        if (threadIdx.x < GO_SLOTS)
            st_bp(&go_slots[threadIdx.x * GO_STRIDE], MAGIC_A);
    } else if (threadIdx.x == 0) {
        const unsigned* myGo = &go_slots[(blockIdx.x & (GO_SLOTS - 1)) * GO_STRIDE];
        long guard = 0;
        while (ld_bp(myGo) != MAGIC_A) {
            __builtin_amdgcn_s_sleep(4);
            if (++guard > SPIN_CAP) break;
        }
    }
    __syncthreads();                       // compiler + wave barrier; no cache ops
    // Phase-2 table reads bypass L1/L2 (IC is the coherence point) -> no acquire needed.

    // ---------------- Phase 2: edge gate, 2 edges/thread ----------------
    {
        const int tid      = blockIdx.x * blockDim.x + threadIdx.x;
        const int nthreads = gridDim.x * blockDim.x;
        const int npair_e  = E >> 1;          // E even (500000)
        for (int p = tid; p < npair_e; p += nthreads) {
            const int2   r2 = ((const int2*)rows)[p];
            const int2   c2 = ((const int2*)cols)[p];
            const int2   t2 = ((const int2*)etype)[p];
            const int2   b2 = ((const int2*)bid)[p];
            const float2 u2 = ((const float2*)eps_u)[p];
            const float a0 = ldf_bp(&s1[r2.x]),   a1 = ldf_bp(&s1[r2.y]);
            const float c0 = ldf_bp(&s2[c2.x]),   c1 = ldf_bp(&s2[c2.y]);
            const float e0 = ldf_bp(&srel[t2.x]), e1 = ldf_bp(&srel[t2.y]);
            const float q0 = ldf_bp(&shq[b2.x]),  q1 = ldf_bp(&shq[b2.y]);

            const float eps0   = fmaf(u2.x, (2.0f * BIAS - 1.0f), (1.0f - BIAS));
            const float eps1   = fmaf(u2.y, (2.0f * BIAS - 1.0f), (1.0f - BIAS));
            const float logit0 = __logf(eps0) - __logf(1.0f - eps0);
            const float logit1 = __logf(eps1) - __logf(1.0f - eps1);
            const float g0 = (logit0 + a0 + c0 + e0 + q0) * TEMP_INV;
            const float g1 = (logit1 + a1 + c1 + e1 + q1) * TEMP_INV;
            float2 o;
            o.x = __builtin_amdgcn_rcpf(1.0f + __expf(-g0));
            o.y = __builtin_amdgcn_rcpf(1.0f + __expf(-g1));
            ((float2*)out)[p] = o;
        }
        if ((E & 1) && tid == 0) {
            const int i = E - 1;
            const float sw  = ldf_bp(&s1[rows[i]]) + ldf_bp(&s2[cols[i]])
                            + ldf_bp(&srel[etype[i]]) + ldf_bp(&shq[bid[i]]);
            const float eps = fmaf(eps_u[i], (2.0f * BIAS - 1.0f), (1.0f - BIAS));
            const float lg  = __logf(eps) - __logf(1.0f - eps);
            const float g   = (lg + sw) * TEMP_INV;
            out[i] = __builtin_amdgcn_rcpf(1.0f + __expf(-g));
        }
    }

    // ---------------- Self-reset (block 0 exits last; kernel-end flush publishes out[]) ----------------
    __syncthreads();
    if (threadIdx.x == 0) st_bp(&flags_done[blockIdx.x], MAGIC_D);
    if (blockIdx.x == 0) {
        for (int s = threadIdx.x; s < GRID_BLOCKS; s += blockDim.x) {
            long guard = 0;
            while (ld_bp(&flags_done[s]) != MAGIC_D) {
                __builtin_amdgcn_s_sleep(4);
                if (++guard > SPIN_CAP) break;
            }
        }
        __syncthreads();   // all done-flags observed before any reset store issues
        for (int s = threadIdx.x; s < GRID_BLOCKS; s += blockDim.x) {
            st_bp(&flags_in[s], 0u);
            st_bp(&flags_done[s], 0u);
        }
        if (threadIdx.x < GO_SLOTS) st_bp(&go_slots[threadIdx.x * GO_STRIDE], 0u);
    }
}

extern "C" void kernel_launch(void* const* d_in, const int* in_sizes, int n_in,
                              void* d_out, int out_size, void* d_ws, size_t ws_size,
                              hipStream_t stream) {
    const float* node_embeds = (const float*)d_in[0];
    const float* R           = (const float*)d_in[1];
    const float* W           = (const float*)d_in[2];
    const float* b           = (const float*)d_in[3];
    const float* eps_u       = (const float*)d_in[4];
    const int*   edge_index  = (const int*)d_in[5];
    const int*   edge_type   = (const int*)d_in[6];
    const int*   batch_id    = (const int*)d_in[7];
    const int*   h_index     = (const int*)d_in[8];
    const int*   r_index     = (const int*)d_in[9];

    const int D       = 128;
    const int n_nodes = in_sizes[0] / D;      // 200000
    const int num_rel = in_sizes[1] / D;      // 200
    const int E       = in_sizes[4];          // 500000
    const int B       = in_sizes[8];          // 256

    const int* rows = edge_index;
    const int* cols = edge_index + E;

    // workspace: s1[N]|s2[N]|srel|shq | align 256B | flags_in[G] | flags_done[G] | go_slots
    float* s1   = (float*)d_ws;
    float* s2   = s1 + n_nodes;
    float* srel = s2 + n_nodes;
    float* shq  = srel + num_rel;
    size_t tbl_bytes = (size_t)(2 * n_nodes + num_rel + B) * sizeof(float);
    tbl_bytes = (tbl_bytes + 255) & ~(size_t)255;
    unsigned* flags_in   = (unsigned*)((char*)d_ws + tbl_bytes);
    unsigned* flags_done = flags_in + GRID_BLOCKS;
    unsigned* go_slots   = flags_done + GRID_BLOCKS;

    hipLaunchKernelGGL(fused_all_kernel, dim3(GRID_BLOCKS), dim3(256), 0, stream,
                       node_embeds, R, W, b, h_index, r_index,
                       rows, cols, edge_type, batch_id, eps_u,
                       s1, s2, srel, shq,
                       flags_in, flags_done, go_slots,
                       (float*)d_out, n_nodes, num_rel, B, E);
}

// Round 8
// 30.609 us; speedup vs baseline: 4.4790x; 1.7206x over previous
//
#include <hip/hip_runtime.h>
#include <math.h>

#define TEMP_INV 0.2f
#define BIAS 0.0001f

// -------- Kernel 1 (fused): node dots + rel table + head/query table
// Super-item space: [0, supers) -> groups of 4 node-pairs (8 nodes, 4KB, loads
//                    issued up-front for MLP)
//                   [supers, supers+num_rel) -> srel rows
//                   [.., +B) -> shq rows
__global__ void fused_dots_kernel(const float* __restrict__ ne,
                                  const float* __restrict__ R,
                                  const float* __restrict__ W,
                                  const float* __restrict__ bias_ptr,
                                  const int* __restrict__ h_index,
                                  const int* __restrict__ r_index,
                                  float* __restrict__ s1,
                                  float* __restrict__ s2,
                                  float* __restrict__ srel,
                                  float* __restrict__ shq,
                                  int n_nodes, int num_rel, int B) {
    const int lane   = threadIdx.x & 63;
    const int l32    = lane & 31;
    const int half   = lane >> 5;                 // which node of the pair
    const int wid    = (blockIdx.x * blockDim.x + threadIdx.x) >> 6;
    const int nwaves = (gridDim.x * blockDim.x) >> 6;

    const int npairs = (n_nodes + 1) >> 1;
    const int supers = (npairs + 3) >> 2;
    const int total  = supers + num_rel + B;

    const float4* W4 = (const float4*)W;
    const float4 w1 = W4[l32];        // W[0:128]
    const float4 w2 = W4[32 + l32];   // W[128:256]

    for (int t = wid; t < total; t += nwaves) {
        if (t < supers) {
            const int pair0 = t * 4;
            float4 e[4];
            int node[4];
            // issue all 4 loads (4KB contiguous per wave) before any reduce
            #pragma unroll
            for (int j = 0; j < 4; ++j) {
                node[j] = (pair0 + j) * 2 + half;
                e[j] = make_float4(0.f, 0.f, 0.f, 0.f);
                if (node[j] < n_nodes)
                    e[j] = ((const float4*)(ne + (size_t)node[j] * 128))[l32];
            }
            #pragma unroll
            for (int j = 0; j < 4; ++j) {
                const float p1 = e[j].x * w1.x + e[j].y * w1.y + e[j].z * w1.z + e[j].w * w1.w;
                const float p2 = e[j].x * w2.x + e[j].y * w2.y + e[j].z * w2.z + e[j].w * w2.w;
                // fold: halves 0-15 reduce p1-sum, 16-31 reduce p2-sum
                const float q1 = __shfl_xor(p1, 16);
                const float q2 = __shfl_xor(p2, 16);
                float a = (l32 < 16) ? (p1 + q1) : (p2 + q2);
                a += __shfl_xor(a, 8);
                a += __shfl_xor(a, 4);
                a += __shfl_xor(a, 2);
                a += __shfl_xor(a, 1);
                if (node[j] < n_nodes) {
                    if (l32 == 0)       s1[node[j]] = a;
                    else if (l32 == 16) s2[node[j]] = a;
                }
            }
        } else if (t < supers + num_rel) {
            const int r = t - supers;
            const float2* W2 = (const float2*)W;
            const float2 w3 = W2[128 + lane];  // W[256:384]
            const float2 e  = ((const float2*)(R + (size_t)r * 128))[lane];
            float p = e.x * w3.x + e.y * w3.y;
            #pragma unroll
            for (int off = 32; off; off >>= 1) p += __shfl_xor(p, off);
            if (lane == 0) srel[r] = p;
        } else {
            const int bb = t - supers - num_rel;
            const float2* W2 = (const float2*)W;
            const float2 w4 = W2[192 + lane];  // W[384:512]
            const float2 w5 = W2[256 + lane];  // W[512:640]
            const float2 h  = ((const float2*)(ne + (size_t)h_index[bb] * 128))[lane];
            const float2 q  = ((const float2*)(R  + (size_t)r_index[bb] * 128))[lane];
            float p = h.x * w4.x + h.y * w4.y + q.x * w5.x + q.y * w5.y;
            #pragma unroll
            for (int off = 32; off; off >>= 1) p += __shfl_xor(p, off);
            if (lane == 0) shq[bb] = p + bias_ptr[0];
        }
    }
}

// -------- Kernel 2: per-edge gate, 2 edges/thread
__device__ __forceinline__ float gate_one(float u, float sw) {
    const float eps   = fmaf(u, (2.0f * BIAS - 1.0f), (1.0f - BIAS));
    // log(eps) - log(1-eps) folded into one transcendental
    const float logit = __logf(eps * __builtin_amdgcn_rcpf(1.0f - eps));
    const float g     = (logit + sw) * TEMP_INV;
    return __builtin_amdgcn_rcpf(1.0f + __expf(-g));
}

__global__ void edge_gate_kernel(const int* __restrict__ rows,
                                 const int* __restrict__ cols,
                                 const int* __restrict__ etype,
                                 const int* __restrict__ bid,
                                 const float* __restrict__ eps_u,
                                 const float* __restrict__ s1,
                                 const float* __restrict__ s2,
                                 const float* __restrict__ srel,
                                 const float* __restrict__ shq,
                                 float* __restrict__ out,
                                 int E) {
    const int tid = blockIdx.x * blockDim.x + threadIdx.x;
    const int i0  = tid * 2;
    if (i0 + 1 < E) {
        const int2   r2 = ((const int2*)rows)[tid];
        const int2   c2 = ((const int2*)cols)[tid];
        const int2   t2 = ((const int2*)etype)[tid];
        const int2   b2 = ((const int2*)bid)[tid];
        const float2 u2 = ((const float2*)eps_u)[tid];
        const float a0 = s1[r2.x],  a1 = s1[r2.y];
        const float c0 = s2[c2.x],  c1 = s2[c2.y];
        const float e0 = srel[t2.x], e1 = srel[t2.y];
        const float q0 = shq[b2.x], q1 = shq[b2.y];
        float2 o;
        o.x = gate_one(u2.x, a0 + c0 + e0 + q0);
        o.y = gate_one(u2.y, a1 + c1 + e1 + q1);
        ((float2*)out)[tid] = o;
    } else if (i0 < E) {
        const float sw = s1[rows[i0]] + s2[cols[i0]] + srel[etype[i0]] + shq[bid[i0]];
        out[i0] = gate_one(eps_u[i0], sw);
    }
}

extern "C" void kernel_launch(void* const* d_in, const int* in_sizes, int n_in,
                              void* d_out, int out_size, void* d_ws, size_t ws_size,
                              hipStream_t stream) {
    const float* node_embeds = (const float*)d_in[0];
    const float* R           = (const float*)d_in[1];
    const float* W           = (const float*)d_in[2];
    const float* b           = (const float*)d_in[3];
    const float* eps_u       = (const float*)d_in[4];
    const int*   edge_index  = (const int*)d_in[5];
    const int*   edge_type   = (const int*)d_in[6];
    const int*   batch_id    = (const int*)d_in[7];
    const int*   h_index     = (const int*)d_in[8];
    const int*   r_index     = (const int*)d_in[9];

    const int D       = 128;
    const int n_nodes = in_sizes[0] / D;      // 200000
    const int num_rel = in_sizes[1] / D;      // 200
    const int E       = in_sizes[4];          // 500000
    const int B       = in_sizes[8];          // 256

    const int* rows = edge_index;
    const int* cols = edge_index + E;

    // workspace layout: s1[N] | s2[N] | srel[num_rel] | shq[B]
    float* s1   = (float*)d_ws;
    float* s2   = s1 + n_nodes;
    float* srel = s2 + n_nodes;
    float* shq  = srel + num_rel;

    // Kernel 1: fused dots. 2048 blocks x 4 waves = 8192 waves (32/CU cap).
    hipLaunchKernelGGL(fused_dots_kernel, dim3(2048), dim3(256), 0, stream,
                       node_embeds, R, W, b, h_index, r_index,
                       s1, s2, srel, shq, n_nodes, num_rel, B);

    // Kernel 2: per-edge, 2 edges/thread -> 977 blocks (~15 waves/CU)
    {
        const int threads = (E + 1) / 2;
        const int grid = (threads + 255) / 256;
        hipLaunchKernelGGL(edge_gate_kernel, dim3(grid), dim3(256), 0, stream,
                           rows, cols, edge_type, batch_id, eps_u,
                           s1, s2, srel, shq, (float*)d_out, E);
    }
}